// Round 9
// baseline (364.262 us; speedup 1.0000x reference)
//
#include <hip/hip_runtime.h>
#include <hip/hip_bf16.h>

#define N_NODES 100000
#define NBUCKET 250
#define BUCKET_W 400              // nodes per dst-bucket (N_NODES/NBUCKET exact)
#define BK_EPT 14                 // edges per thread in bucket pass
#define SRC_PASSES 16
#define SRC_W ((N_NODES + SRC_PASSES - 1) / SRC_PASSES)   // 6250

typedef __attribute__((ext_vector_type(8))) short short8;     // 8 bf16 (4 VGPRs)
typedef __attribute__((ext_vector_type(8))) unsigned short u16x8;
typedef __attribute__((ext_vector_type(4))) unsigned short u16x4;
typedef __attribute__((ext_vector_type(4))) float floatx4;

__device__ __forceinline__ float b2f(unsigned short u) {
    return __uint_as_float(((unsigned int)u) << 16);
}
__device__ __forceinline__ unsigned short f2b(float f) {   // RNE
    unsigned int u = __float_as_uint(f);
    unsigned int r = u + 0x7FFFu + ((u >> 16) & 1u);
    return (unsigned short)(r >> 16);
}

// ===========================================================================
// Fused prep: x->bf16 cast  |  fragment-major weight swizzle  |  bucket cursor
// init. Branch on blockIdx range (all independent).
__global__ __launch_bounds__(256) void prep_kernel(
    const float* __restrict__ x,
    const float* __restrict__ W1l, const float* __restrict__ W1r,
    const float* __restrict__ W2l, const float* __restrict__ W2r,
    unsigned short* __restrict__ xb, unsigned short* __restrict__ Wc1f,
    unsigned short* __restrict__ W2lf, unsigned short* __restrict__ W2rf,
    int* __restrict__ bucketCursor, int pairCap)
{
    int blk = blockIdx.x;
    if (blk < 12500) {
        int tid = blk * 256 + threadIdx.x;          // one float4 per thread
        float4 v = ((const float4*)x)[tid];
        u16x4 o;
        o.x = f2b(v.x); o.y = f2b(v.y); o.z = f2b(v.z); o.w = f2b(v.w);
        ((u16x4*)xb)[tid] = o;
    } else if (blk < 12692) {
        int tid = (blk - 12500) * 256 + threadIdx.x;
        if (tid < 32768) {                 // 8 ks * 8 t * 64 lane * 8 j
            int j = tid & 7, lane = (tid >> 3) & 63, t = (tid >> 9) & 7, ks = tid >> 12;
            int m = lane & 15, quad = lane >> 4;
            int row = t * 16 + m;
            int k = ks * 32 + quad * 8 + j;
            float v = (k < 128) ? W1l[row * 128 + k] : W1r[row * 128 + (k - 128)];
            Wc1f[tid] = f2b(v);
        } else if (tid < 40960) {          // 4 ks * 4 t * 64 lane * 8 j
            int idx = tid - 32768;
            int j = idx & 7, lane = (idx >> 3) & 63, t = (idx >> 9) & 3, ks = idx >> 11;
            int m = lane & 15, quad = lane >> 4;
            int row = t * 16 + m;
            int k = ks * 32 + quad * 8 + j;
            W2lf[idx] = f2b(W2l[row * 128 + k]);
        } else if (tid < 49152) {
            int idx = tid - 40960;
            int j = idx & 7, lane = (idx >> 3) & 63, t = (idx >> 9) & 3, ks = idx >> 11;
            int m = lane & 15, quad = lane >> 4;
            int row = t * 16 + m;
            int k = ks * 32 + quad * 8 + j;
            W2rf[idx] = f2b(W2r[row * 128 + k]);
        }
    } else {
        if (threadIdx.x < NBUCKET)
            bucketCursor[threadIdx.x] = threadIdx.x * pairCap;
    }
}

// ===========================================================================
// Pass 1: bucket edges into fixed-capacity per-bucket regions of pairs[].
// Block-local LDS rank + one global atomic per (block,bucket) -> each block
// writes exclusive contiguous chunks (clean full-line write-backs).
__global__ __launch_bounds__(1024) void bucket_kernel(
    const int* __restrict__ src, const int* __restrict__ dst,
    int* __restrict__ bucketCursor, int2* __restrict__ pairs, int E)
{
    __shared__ int cnt[NBUCKET];
    __shared__ int base[NBUCKET];
    const int EPB = 1024 * BK_EPT;
    int e0 = blockIdx.x * EPB;
    for (int t = threadIdx.x; t < NBUCKET; t += 1024) cnt[t] = 0;
    __syncthreads();

    int es[BK_EPT], ed[BK_EPT], rk[BK_EPT], bk[BK_EPT];
    #pragma unroll
    for (int j = 0; j < BK_EPT; j++) {
        int i = e0 + j * 1024 + threadIdx.x;
        if (i < E) {
            es[j] = src[i];
            ed[j] = dst[i];
            bk[j] = ed[j] / BUCKET_W;
            rk[j] = atomicAdd(&cnt[bk[j]], 1);
        } else {
            bk[j] = -1;
        }
    }
    __syncthreads();
    for (int t = threadIdx.x; t < NBUCKET; t += 1024)
        base[t] = atomicAdd(&bucketCursor[t], cnt[t]);
    __syncthreads();

    #pragma unroll
    for (int j = 0; j < BK_EPT; j++) {
        if (bk[j] >= 0)
            pairs[(size_t)base[bk[j]] + rk[j]] = make_int2(es[j], ed[j]);
    }
}

// ===========================================================================
// Pass 2: one block per bucket. LDS hist over the bucket's 400 nodes, LDS
// exclusive scan, LDS cursors -> place src ids into edge_src and emit
// per-node (beg, deg). NEW: placement runs in SRC_PASSES sequential
// src-range sweeps, so every node's edge list comes out coarsely SORTED BY
// SRC. During the gathers, all resident waves walk their lists front-to-back
// in soft lockstep -> the active src read-window is ~SRC_W rows (1.6 MB),
// which fits each XCD's L2 (fixes the 6x L2 oversubscription / 260 MB
// L3 re-fetch seen in round 8).
__global__ __launch_bounds__(1024) void fill_kernel(
    const int2* __restrict__ pairs, const int* __restrict__ bucketCursor,
    int* __restrict__ edge_src, int2* __restrict__ nodeInfo, int pairCap)
{
    __shared__ int hist[BUCKET_W];
    __shared__ int off[BUCKET_W];
    __shared__ int cur[BUCKET_W];
    int b = blockIdx.x;
    int t = threadIdx.x;
    int base = b * pairCap;
    int cnt = bucketCursor[b] - base;
    int node0 = b * BUCKET_W;

    if (t < BUCKET_W) hist[t] = 0;
    __syncthreads();
    for (int i = t; i < cnt; i += 1024)
        atomicAdd(&hist[pairs[base + i].y - node0], 1);
    __syncthreads();

    if (t < BUCKET_W) off[t] = hist[t];
    __syncthreads();
    for (int o = 1; o < BUCKET_W; o <<= 1) {
        int v = 0;
        if (t < BUCKET_W && t >= o) v = off[t - o];
        __syncthreads();
        if (t < BUCKET_W && t >= o) off[t] += v;
        __syncthreads();
    }
    if (t < BUCKET_W) {
        int gb = base + off[t] - hist[t];     // exclusive prefix
        cur[t] = gb;
        nodeInfo[node0 + t] = make_int2(gb, hist[t]);
    }
    __syncthreads();

    // src-range ordered placement (lists come out 16-way src-sorted).
    for (int p = 0; p < SRC_PASSES; p++) {
        int lo = p * SRC_W;
        int hi = lo + SRC_W;
        for (int i = t; i < cnt; i += 1024) {
            int2 pr = pairs[base + i];
            if (pr.x >= lo && pr.x < hi) {
                int pos = atomicAdd(&cur[pr.y - node0], 1);
                edge_src[pos] = pr.x;
            }
        }
        __syncthreads();
    }
}

// ===========================================================================
// bf16 gather mean-aggregation, unroll-4. L lanes/node, 8 bf16 per lane,
// D = 8*L. Output pre-divided by max(deg,1).
template<int L>
__global__ __launch_bounds__(256) void gather_agg_kernel(
    const unsigned short* __restrict__ feat, const int* __restrict__ edge_src,
    const int2* __restrict__ nodeInfo, unsigned short* __restrict__ aggOut)
{
    int tid = blockIdx.x * 256 + threadIdx.x;
    int node = tid / L;
    int q = tid % L;
    int2 info = nodeInfo[node];
    int e = info.x, deg = info.y, end = info.x + deg;
    const u16x8* f8 = (const u16x8*)feat;
    float acc[8];
    #pragma unroll
    for (int j = 0; j < 8; j++) acc[j] = 0.0f;
    for (; e + 4 <= end; e += 4) {
        int s0 = edge_src[e + 0];
        int s1 = edge_src[e + 1];
        int s2 = edge_src[e + 2];
        int s3 = edge_src[e + 3];
        u16x8 v0 = f8[(size_t)s0 * L + q];
        u16x8 v1 = f8[(size_t)s1 * L + q];
        u16x8 v2 = f8[(size_t)s2 * L + q];
        u16x8 v3 = f8[(size_t)s3 * L + q];
        #pragma unroll
        for (int j = 0; j < 8; j++)
            acc[j] += (b2f(v0[j]) + b2f(v1[j])) + (b2f(v2[j]) + b2f(v3[j]));
    }
    for (; e < end; e++) {
        u16x8 v0 = f8[(size_t)edge_src[e] * L + q];
        #pragma unroll
        for (int j = 0; j < 8; j++) acc[j] += b2f(v0[j]);
    }
    float inv = (deg > 0) ? 1.0f / (float)deg : 0.0f;
    u16x8 o;
    #pragma unroll
    for (int j = 0; j < 8; j++) o[j] = f2b(acc[j] * inv);
    ((u16x8*)aggOut)[(size_t)node * L + q] = o;
}

// ===========================================================================
// Fused dense block (fragment-major weights, 32 nodes/wave).
__global__ __launch_bounds__(256) void fused_l1_kernel(
    const unsigned short* __restrict__ a1b, const unsigned short* __restrict__ xb,
    const unsigned short* __restrict__ Wc1f, const float* __restrict__ b1,
    const unsigned short* __restrict__ W2lf, const unsigned short* __restrict__ W2rf,
    unsigned short* __restrict__ g2b, unsigned short* __restrict__ r2b)
{
    __shared__ unsigned short h_lds[4][32][136];

    int wave = threadIdx.x >> 6;
    int lane = threadIdx.x & 63;
    int m    = lane & 15;
    int quad = lane >> 4;
    int node0 = blockIdx.x * 128 + wave * 32;

    int n0 = min(node0 + m,      N_NODES - 1);
    int n1 = min(node0 + 16 + m, N_NODES - 1);

    floatx4 acc[2][8];
    #pragma unroll
    for (int mt = 0; mt < 2; mt++)
        #pragma unroll
        for (int t = 0; t < 8; t++) acc[mt][t] = (floatx4)(0.0f);

    #pragma unroll
    for (int ks = 0; ks < 8; ks++) {
        int k0 = ks * 32 + quad * 8;
        const unsigned short* s = (ks < 4) ? a1b : xb;
        int koff = (ks < 4) ? k0 : (k0 - 128);
        short8 af0 = *(const short8*)(s + (size_t)n0 * 128 + koff);
        short8 af1 = *(const short8*)(s + (size_t)n1 * 128 + koff);
        #pragma unroll
        for (int t = 0; t < 8; t++) {
            short8 bf = *(const short8*)(Wc1f + (((ks * 8 + t) * 64 + lane) << 3));
            acc[0][t] = __builtin_amdgcn_mfma_f32_16x16x32_bf16(af0, bf, acc[0][t], 0, 0, 0);
            acc[1][t] = __builtin_amdgcn_mfma_f32_16x16x32_bf16(af1, bf, acc[1][t], 0, 0, 0);
        }
    }

    #pragma unroll
    for (int t = 0; t < 8; t++) {
        int j = t * 16 + m;
        float bias = b1[j];
        #pragma unroll
        for (int mt = 0; mt < 2; mt++) {
            #pragma unroll
            for (int r = 0; r < 4; r++) {
                int row = mt * 16 + quad * 4 + r;
                h_lds[wave][row][j] = f2b(fmaxf(acc[mt][t][r] + bias, 0.0f));
            }
        }
    }
    __syncthreads();

    floatx4 acc2[2][4], acc3[2][4];
    #pragma unroll
    for (int mt = 0; mt < 2; mt++)
        #pragma unroll
        for (int t = 0; t < 4; t++) { acc2[mt][t] = (floatx4)(0.0f); acc3[mt][t] = (floatx4)(0.0f); }

    #pragma unroll
    for (int ks = 0; ks < 4; ks++) {
        int k0 = ks * 32 + quad * 8;
        short8 hf0 = *(const short8*)&h_lds[wave][m][k0];
        short8 hf1 = *(const short8*)&h_lds[wave][16 + m][k0];
        #pragma unroll
        for (int t = 0; t < 4; t++) {
            short8 bl = *(const short8*)(W2lf + (((ks * 4 + t) * 64 + lane) << 3));
            short8 br = *(const short8*)(W2rf + (((ks * 4 + t) * 64 + lane) << 3));
            acc2[0][t] = __builtin_amdgcn_mfma_f32_16x16x32_bf16(hf0, bl, acc2[0][t], 0, 0, 0);
            acc2[1][t] = __builtin_amdgcn_mfma_f32_16x16x32_bf16(hf1, bl, acc2[1][t], 0, 0, 0);
            acc3[0][t] = __builtin_amdgcn_mfma_f32_16x16x32_bf16(hf0, br, acc3[0][t], 0, 0, 0);
            acc3[1][t] = __builtin_amdgcn_mfma_f32_16x16x32_bf16(hf1, br, acc3[1][t], 0, 0, 0);
        }
    }

    #pragma unroll
    for (int mt = 0; mt < 2; mt++) {
        #pragma unroll
        for (int t = 0; t < 4; t++) {
            #pragma unroll
            for (int r = 0; r < 4; r++) {
                int n = node0 + mt * 16 + quad * 4 + r;
                if (n < N_NODES) {
                    g2b[(size_t)n * 64 + t * 16 + m] = f2b(acc2[mt][t][r]);
                    r2b[(size_t)n * 64 + t * 16 + m] = f2b(acc3[mt][t][r]);
                }
            }
        }
    }
}

// ===========================================================================
// Layer-2 gather (L=8) fused with bias + residual + log_softmax.
__global__ __launch_bounds__(256) void gather_final_kernel(
    const unsigned short* __restrict__ g2b, const int* __restrict__ edge_src,
    const int2* __restrict__ nodeInfo, const unsigned short* __restrict__ r2b,
    const float* __restrict__ b2, float* __restrict__ out)
{
    int tid = blockIdx.x * 256 + threadIdx.x;
    int node = tid >> 3;
    int q = tid & 7;
    int2 info = nodeInfo[node];
    int e = info.x, deg = info.y, end = info.x + deg;
    const u16x8* f8 = (const u16x8*)g2b;
    float acc[8];
    #pragma unroll
    for (int j = 0; j < 8; j++) acc[j] = 0.0f;
    for (; e + 4 <= end; e += 4) {
        int s0 = edge_src[e + 0];
        int s1 = edge_src[e + 1];
        int s2 = edge_src[e + 2];
        int s3 = edge_src[e + 3];
        u16x8 v0 = f8[(size_t)s0 * 8 + q];
        u16x8 v1 = f8[(size_t)s1 * 8 + q];
        u16x8 v2 = f8[(size_t)s2 * 8 + q];
        u16x8 v3 = f8[(size_t)s3 * 8 + q];
        #pragma unroll
        for (int j = 0; j < 8; j++)
            acc[j] += (b2f(v0[j]) + b2f(v1[j])) + (b2f(v2[j]) + b2f(v3[j]));
    }
    for (; e < end; e++) {
        u16x8 v0 = f8[(size_t)edge_src[e] * 8 + q];
        #pragma unroll
        for (int j = 0; j < 8; j++) acc[j] += b2f(v0[j]);
    }
    float inv = (deg > 0) ? 1.0f / (float)deg : 0.0f;

    u16x8 rv = ((const u16x8*)r2b)[tid];            // node*8 + q
    float4 blo = ((const float4*)b2)[q * 2];
    float4 bhi = ((const float4*)b2)[q * 2 + 1];
    float v[8];
    v[0] = acc[0] * inv + blo.x + b2f(rv[0]);
    v[1] = acc[1] * inv + blo.y + b2f(rv[1]);
    v[2] = acc[2] * inv + blo.z + b2f(rv[2]);
    v[3] = acc[3] * inv + blo.w + b2f(rv[3]);
    v[4] = acc[4] * inv + bhi.x + b2f(rv[4]);
    v[5] = acc[5] * inv + bhi.y + b2f(rv[5]);
    v[6] = acc[6] * inv + bhi.z + b2f(rv[6]);
    v[7] = acc[7] * inv + bhi.w + b2f(rv[7]);

    float mx = v[0];
    #pragma unroll
    for (int j = 1; j < 8; j++) mx = fmaxf(mx, v[j]);
    mx = fmaxf(mx, __shfl_xor(mx, 1, 64));
    mx = fmaxf(mx, __shfl_xor(mx, 2, 64));
    mx = fmaxf(mx, __shfl_xor(mx, 4, 64));
    float s = 0.0f;
    #pragma unroll
    for (int j = 0; j < 8; j++) s += expf(v[j] - mx);
    s += __shfl_xor(s, 1, 64);
    s += __shfl_xor(s, 2, 64);
    s += __shfl_xor(s, 4, 64);
    float lg = mx + logf(s);

    float4 o0 = make_float4(v[0] - lg, v[1] - lg, v[2] - lg, v[3] - lg);
    float4 o1 = make_float4(v[4] - lg, v[5] - lg, v[6] - lg, v[7] - lg);
    float4* op = (float4*)(out + (size_t)node * 64 + q * 8);
    op[0] = o0;
    op[1] = o1;
}

// ===========================================================================
extern "C" void kernel_launch(void* const* d_in, const int* in_sizes, int n_in,
                              void* d_out, int out_size, void* d_ws, size_t ws_size,
                              hipStream_t stream)
{
    const float* x   = (const float*)d_in[0];
    const int*   ei  = (const int*)d_in[1];
    const float* W1l = (const float*)d_in[2];
    const float* b1  = (const float*)d_in[3];
    const float* W1r = (const float*)d_in[4];
    const float* W2l = (const float*)d_in[5];
    const float* b2  = (const float*)d_in[6];
    const float* W2r = (const float*)d_in[7];
    float* out = (float*)d_out;

    int E = in_sizes[1] / 2;
    const int* src = ei;
    const int* dst = ei + E;

    // Per-bucket pair capacity: 1.5x mean (mean 6400, sigma 80 -> +40 sigma).
    int pairCap = ((E / NBUCKET) * 3 / 2 + 255) / 256 * 256;   // 9600 for E=1.6M

    // Workspace layout (16B-aligned sections)
    char* ws = (char*)d_ws;
    int*  bucketCursor = (int*)ws;   ws += ((size_t)NBUCKET * 4 + 15) / 16 * 16;
    int2* pairs        = (int2*)ws;  ws += (size_t)NBUCKET * pairCap * 8;
    int*  edge_src     = (int*)ws;   ws += (size_t)NBUCKET * pairCap * 4;
    int2* nodeInfo     = (int2*)ws;  ws += (size_t)N_NODES * 8;
    unsigned short* xb   = (unsigned short*)ws;  ws += (size_t)N_NODES * 128 * 2;
    unsigned short* a1b  = (unsigned short*)ws;  ws += (size_t)N_NODES * 128 * 2;
    unsigned short* g2b  = (unsigned short*)ws;  ws += (size_t)N_NODES * 64 * 2;
    unsigned short* r2b  = (unsigned short*)ws;  ws += (size_t)N_NODES * 64 * 2;
    unsigned short* Wc1f = (unsigned short*)ws;  ws += 128 * 256 * 2;
    unsigned short* W2lf = (unsigned short*)ws;  ws += 64 * 128 * 2;
    unsigned short* W2rf = (unsigned short*)ws;  ws += 64 * 128 * 2;

    // 1. prep: bf16 casts + weight swizzle + bucket cursor init
    prep_kernel<<<12693, 256, 0, stream>>>(
        x, W1l, W1r, W2l, W2r, xb, Wc1f, W2lf, W2rf, bucketCursor, pairCap);

    // 2. bucket edges by dst range (block-exclusive chunk writes)
    {
        const int EPB = 1024 * BK_EPT;
        bucket_kernel<<<(E + EPB - 1) / EPB, 1024, 0, stream>>>(
            src, dst, bucketCursor, pairs, E);
    }

    // 3. per-bucket LDS hist/scan + src-range-ordered place -> edge_src
    fill_kernel<<<NBUCKET, 1024, 0, stream>>>(
        pairs, bucketCursor, edge_src, nodeInfo, pairCap);

    // 4. layer-1 aggregation (D=128, 16 lanes/node)
    gather_agg_kernel<16><<<(N_NODES * 16) / 256, 256, 0, stream>>>(
        xb, edge_src, nodeInfo, a1b);

    // 5. fused dense block: layer1 GEMM + relu + both layer2 matmuls
    fused_l1_kernel<<<(N_NODES + 127) / 128, 256, 0, stream>>>(
        a1b, xb, Wc1f, b1, W2lf, W2rf, g2b, r2b);

    // 6. layer-2 aggregation fused with bias + residual + log_softmax
    gather_final_kernel<<<(N_NODES * 8) / 256, 256, 0, stream>>>(
        g2b, edge_src, nodeInfo, r2b, b2, out);
}

// Round 10
// 307.586 us; speedup vs baseline: 1.1843x; 1.1843x over previous
//
#include <hip/hip_runtime.h>
#include <hip/hip_bf16.h>

#define N_NODES 100000
#define NBUCKET 250
#define BUCKET_W 400              // nodes per dst-bucket (N_NODES/NBUCKET exact)
#define BK_EPT 14                 // edges per thread in bucket pass

typedef __attribute__((ext_vector_type(8))) short short8;     // 8 bf16 (4 VGPRs)
typedef __attribute__((ext_vector_type(8))) unsigned short u16x8;
typedef __attribute__((ext_vector_type(4))) unsigned short u16x4;
typedef __attribute__((ext_vector_type(4))) float floatx4;
typedef __attribute__((ext_vector_type(2))) float floatx2;

__device__ __forceinline__ float b2f(unsigned short u) {
    return __uint_as_float(((unsigned int)u) << 16);
}
__device__ __forceinline__ unsigned short f2b(float f) {   // RNE
    unsigned int u = __float_as_uint(f);
    unsigned int r = u + 0x7FFFu + ((u >> 16) & 1u);
    return (unsigned short)(r >> 16);
}

// ===========================================================================
// Fused prep: x->bf16 + x->fp8(e4m3) casts | fragment-major weight swizzle |
// bucket cursor init. Branch on blockIdx range (all independent).
__global__ __launch_bounds__(256) void prep_kernel(
    const float* __restrict__ x,
    const float* __restrict__ W1l, const float* __restrict__ W1r,
    const float* __restrict__ W2l, const float* __restrict__ W2r,
    unsigned short* __restrict__ xb, unsigned char* __restrict__ xq,
    unsigned short* __restrict__ Wc1f,
    unsigned short* __restrict__ W2lf, unsigned short* __restrict__ W2rf,
    int* __restrict__ bucketCursor, int pairCap)
{
    int blk = blockIdx.x;
    if (blk < 12500) {
        int tid = blk * 256 + threadIdx.x;          // one float4 per thread
        float4 v = ((const float4*)x)[tid];
        u16x4 o;
        o.x = f2b(v.x); o.y = f2b(v.y); o.z = f2b(v.z); o.w = f2b(v.w);
        ((u16x4*)xb)[tid] = o;
        // fp8 e4m3 (OCP on gfx950) pack: 4 floats -> 4 bytes
        int p = 0;
        p = __builtin_amdgcn_cvt_pk_fp8_f32(v.x, v.y, p, false);  // bytes 0,1
        p = __builtin_amdgcn_cvt_pk_fp8_f32(v.z, v.w, p, true);   // bytes 2,3
        ((unsigned int*)xq)[tid] = (unsigned int)p;
    } else if (blk < 12692) {
        int tid = (blk - 12500) * 256 + threadIdx.x;
        if (tid < 32768) {                 // 8 ks * 8 t * 64 lane * 8 j
            int j = tid & 7, lane = (tid >> 3) & 63, t = (tid >> 9) & 7, ks = tid >> 12;
            int m = lane & 15, quad = lane >> 4;
            int row = t * 16 + m;
            int k = ks * 32 + quad * 8 + j;
            float v = (k < 128) ? W1l[row * 128 + k] : W1r[row * 128 + (k - 128)];
            Wc1f[tid] = f2b(v);
        } else if (tid < 40960) {          // 4 ks * 4 t * 64 lane * 8 j
            int idx = tid - 32768;
            int j = idx & 7, lane = (idx >> 3) & 63, t = (idx >> 9) & 3, ks = idx >> 11;
            int m = lane & 15, quad = lane >> 4;
            int row = t * 16 + m;
            int k = ks * 32 + quad * 8 + j;
            W2lf[idx] = f2b(W2l[row * 128 + k]);
        } else if (tid < 49152) {
            int idx = tid - 40960;
            int j = idx & 7, lane = (idx >> 3) & 63, t = (idx >> 9) & 3, ks = idx >> 11;
            int m = lane & 15, quad = lane >> 4;
            int row = t * 16 + m;
            int k = ks * 32 + quad * 8 + j;
            W2rf[idx] = f2b(W2r[row * 128 + k]);
        }
    } else {
        if (threadIdx.x < NBUCKET)
            bucketCursor[threadIdx.x] = threadIdx.x * pairCap;
    }
}

// ===========================================================================
// Pass 1: bucket edges into fixed-capacity per-bucket regions of pairs[].
__global__ __launch_bounds__(1024) void bucket_kernel(
    const int* __restrict__ src, const int* __restrict__ dst,
    int* __restrict__ bucketCursor, int2* __restrict__ pairs, int E)
{
    __shared__ int cnt[NBUCKET];
    __shared__ int base[NBUCKET];
    const int EPB = 1024 * BK_EPT;
    int e0 = blockIdx.x * EPB;
    for (int t = threadIdx.x; t < NBUCKET; t += 1024) cnt[t] = 0;
    __syncthreads();

    int es[BK_EPT], ed[BK_EPT], rk[BK_EPT], bk[BK_EPT];
    #pragma unroll
    for (int j = 0; j < BK_EPT; j++) {
        int i = e0 + j * 1024 + threadIdx.x;
        if (i < E) {
            es[j] = src[i];
            ed[j] = dst[i];
            bk[j] = ed[j] / BUCKET_W;
            rk[j] = atomicAdd(&cnt[bk[j]], 1);
        } else {
            bk[j] = -1;
        }
    }
    __syncthreads();
    for (int t = threadIdx.x; t < NBUCKET; t += 1024)
        base[t] = atomicAdd(&bucketCursor[t], cnt[t]);
    __syncthreads();

    #pragma unroll
    for (int j = 0; j < BK_EPT; j++) {
        if (bk[j] >= 0)
            pairs[(size_t)base[bk[j]] + rk[j]] = make_int2(es[j], ed[j]);
    }
}

// ===========================================================================
// Pass 2 (R8 version — single placement pass): one block per bucket. LDS hist
// over the bucket's 400 nodes, LDS scan, LDS cursors -> edge_src + nodeInfo.
__global__ __launch_bounds__(1024) void fill_kernel(
    const int2* __restrict__ pairs, const int* __restrict__ bucketCursor,
    int* __restrict__ edge_src, int2* __restrict__ nodeInfo, int pairCap)
{
    __shared__ int hist[BUCKET_W];
    __shared__ int off[BUCKET_W];
    __shared__ int cur[BUCKET_W];
    int b = blockIdx.x;
    int t = threadIdx.x;
    int base = b * pairCap;
    int cnt = bucketCursor[b] - base;
    int node0 = b * BUCKET_W;

    if (t < BUCKET_W) hist[t] = 0;
    __syncthreads();
    for (int i = t; i < cnt; i += 1024)
        atomicAdd(&hist[pairs[base + i].y - node0], 1);
    __syncthreads();

    if (t < BUCKET_W) off[t] = hist[t];
    __syncthreads();
    for (int o = 1; o < BUCKET_W; o <<= 1) {
        int v = 0;
        if (t < BUCKET_W && t >= o) v = off[t - o];
        __syncthreads();
        if (t < BUCKET_W && t >= o) off[t] += v;
        __syncthreads();
    }
    if (t < BUCKET_W) {
        int gb = base + off[t] - hist[t];     // exclusive prefix
        cur[t] = gb;
        nodeInfo[node0 + t] = make_int2(gb, hist[t]);
    }
    __syncthreads();

    for (int i = t; i < cnt; i += 1024) {
        int2 p = pairs[base + i];
        int pos = atomicAdd(&cur[p.y - node0], 1);
        edge_src[pos] = p.x;
    }
}

// ===========================================================================
// Layer-1 gather mean-aggregation from the FP8 table (half the bytes of bf16).
// 8 lanes/node, 16 fp8 (16 B) per lane; fp32 accumulate via v_cvt_pk_f32_fp8;
// output bf16, pre-divided by max(deg,1).
__global__ __launch_bounds__(256) void gather_fp8_kernel(
    const unsigned char* __restrict__ xq, const int* __restrict__ edge_src,
    const int2* __restrict__ nodeInfo, unsigned short* __restrict__ aggOut)
{
    int tid = blockIdx.x * 256 + threadIdx.x;
    int node = tid >> 3;
    int q = tid & 7;
    int2 info = nodeInfo[node];
    int e = info.x, deg = info.y, end = info.x + deg;
    const uint4* f16 = (const uint4*)xq;      // 16 fp8 per uint4

    float acc[16];
    #pragma unroll
    for (int j = 0; j < 16; j++) acc[j] = 0.0f;

    #define ACC16(W)  do {                                                   \
        floatx2 p;                                                           \
        p = __builtin_amdgcn_cvt_pk_f32_fp8((W).x, false); acc[0]+=p.x; acc[1]+=p.y;  \
        p = __builtin_amdgcn_cvt_pk_f32_fp8((W).x, true);  acc[2]+=p.x; acc[3]+=p.y;  \
        p = __builtin_amdgcn_cvt_pk_f32_fp8((W).y, false); acc[4]+=p.x; acc[5]+=p.y;  \
        p = __builtin_amdgcn_cvt_pk_f32_fp8((W).y, true);  acc[6]+=p.x; acc[7]+=p.y;  \
        p = __builtin_amdgcn_cvt_pk_f32_fp8((W).z, false); acc[8]+=p.x; acc[9]+=p.y;  \
        p = __builtin_amdgcn_cvt_pk_f32_fp8((W).z, true);  acc[10]+=p.x; acc[11]+=p.y;\
        p = __builtin_amdgcn_cvt_pk_f32_fp8((W).w, false); acc[12]+=p.x; acc[13]+=p.y;\
        p = __builtin_amdgcn_cvt_pk_f32_fp8((W).w, true);  acc[14]+=p.x; acc[15]+=p.y;\
    } while (0)

    for (; e + 4 <= end; e += 4) {
        int s0 = edge_src[e + 0];
        int s1 = edge_src[e + 1];
        int s2 = edge_src[e + 2];
        int s3 = edge_src[e + 3];
        uint4 w0 = f16[(size_t)s0 * 8 + q];
        uint4 w1 = f16[(size_t)s1 * 8 + q];
        uint4 w2 = f16[(size_t)s2 * 8 + q];
        uint4 w3 = f16[(size_t)s3 * 8 + q];
        ACC16(w0); ACC16(w1); ACC16(w2); ACC16(w3);
    }
    for (; e < end; e++) {
        uint4 w0 = f16[(size_t)edge_src[e] * 8 + q];
        ACC16(w0);
    }
    #undef ACC16

    float inv = (deg > 0) ? 1.0f / (float)deg : 0.0f;
    u16x8 o0, o1;
    #pragma unroll
    for (int j = 0; j < 8; j++) { o0[j] = f2b(acc[j] * inv); o1[j] = f2b(acc[8 + j] * inv); }
    u16x8* op = (u16x8*)(aggOut + (size_t)node * 128 + q * 16);
    op[0] = o0;
    op[1] = o1;
}

// ===========================================================================
// Fused dense block (fragment-major weights, 32 nodes/wave).
__global__ __launch_bounds__(256) void fused_l1_kernel(
    const unsigned short* __restrict__ a1b, const unsigned short* __restrict__ xb,
    const unsigned short* __restrict__ Wc1f, const float* __restrict__ b1,
    const unsigned short* __restrict__ W2lf, const unsigned short* __restrict__ W2rf,
    unsigned short* __restrict__ g2b, unsigned short* __restrict__ r2b)
{
    __shared__ unsigned short h_lds[4][32][136];

    int wave = threadIdx.x >> 6;
    int lane = threadIdx.x & 63;
    int m    = lane & 15;
    int quad = lane >> 4;
    int node0 = blockIdx.x * 128 + wave * 32;

    int n0 = min(node0 + m,      N_NODES - 1);
    int n1 = min(node0 + 16 + m, N_NODES - 1);

    floatx4 acc[2][8];
    #pragma unroll
    for (int mt = 0; mt < 2; mt++)
        #pragma unroll
        for (int t = 0; t < 8; t++) acc[mt][t] = (floatx4)(0.0f);

    #pragma unroll
    for (int ks = 0; ks < 8; ks++) {
        int k0 = ks * 32 + quad * 8;
        const unsigned short* s = (ks < 4) ? a1b : xb;
        int koff = (ks < 4) ? k0 : (k0 - 128);
        short8 af0 = *(const short8*)(s + (size_t)n0 * 128 + koff);
        short8 af1 = *(const short8*)(s + (size_t)n1 * 128 + koff);
        #pragma unroll
        for (int t = 0; t < 8; t++) {
            short8 bf = *(const short8*)(Wc1f + (((ks * 8 + t) * 64 + lane) << 3));
            acc[0][t] = __builtin_amdgcn_mfma_f32_16x16x32_bf16(af0, bf, acc[0][t], 0, 0, 0);
            acc[1][t] = __builtin_amdgcn_mfma_f32_16x16x32_bf16(af1, bf, acc[1][t], 0, 0, 0);
        }
    }

    #pragma unroll
    for (int t = 0; t < 8; t++) {
        int j = t * 16 + m;
        float bias = b1[j];
        #pragma unroll
        for (int mt = 0; mt < 2; mt++) {
            #pragma unroll
            for (int r = 0; r < 4; r++) {
                int row = mt * 16 + quad * 4 + r;
                h_lds[wave][row][j] = f2b(fmaxf(acc[mt][t][r] + bias, 0.0f));
            }
        }
    }
    __syncthreads();

    floatx4 acc2[2][4], acc3[2][4];
    #pragma unroll
    for (int mt = 0; mt < 2; mt++)
        #pragma unroll
        for (int t = 0; t < 4; t++) { acc2[mt][t] = (floatx4)(0.0f); acc3[mt][t] = (floatx4)(0.0f); }

    #pragma unroll
    for (int ks = 0; ks < 4; ks++) {
        int k0 = ks * 32 + quad * 8;
        short8 hf0 = *(const short8*)&h_lds[wave][m][k0];
        short8 hf1 = *(const short8*)&h_lds[wave][16 + m][k0];
        #pragma unroll
        for (int t = 0; t < 4; t++) {
            short8 bl = *(const short8*)(W2lf + (((ks * 4 + t) * 64 + lane) << 3));
            short8 br = *(const short8*)(W2rf + (((ks * 4 + t) * 64 + lane) << 3));
            acc2[0][t] = __builtin_amdgcn_mfma_f32_16x16x32_bf16(hf0, bl, acc2[0][t], 0, 0, 0);
            acc2[1][t] = __builtin_amdgcn_mfma_f32_16x16x32_bf16(hf1, bl, acc2[1][t], 0, 0, 0);
            acc3[0][t] = __builtin_amdgcn_mfma_f32_16x16x32_bf16(hf0, br, acc3[0][t], 0, 0, 0);
            acc3[1][t] = __builtin_amdgcn_mfma_f32_16x16x32_bf16(hf1, br, acc3[1][t], 0, 0, 0);
        }
    }

    #pragma unroll
    for (int mt = 0; mt < 2; mt++) {
        #pragma unroll
        for (int t = 0; t < 4; t++) {
            #pragma unroll
            for (int r = 0; r < 4; r++) {
                int n = node0 + mt * 16 + quad * 4 + r;
                if (n < N_NODES) {
                    g2b[(size_t)n * 64 + t * 16 + m] = f2b(acc2[mt][t][r]);
                    r2b[(size_t)n * 64 + t * 16 + m] = f2b(acc3[mt][t][r]);
                }
            }
        }
    }
}

// ===========================================================================
// Layer-2 gather (L=8, bf16) fused with bias + residual + log_softmax.
__global__ __launch_bounds__(256) void gather_final_kernel(
    const unsigned short* __restrict__ g2b, const int* __restrict__ edge_src,
    const int2* __restrict__ nodeInfo, const unsigned short* __restrict__ r2b,
    const float* __restrict__ b2, float* __restrict__ out)
{
    int tid = blockIdx.x * 256 + threadIdx.x;
    int node = tid >> 3;
    int q = tid & 7;
    int2 info = nodeInfo[node];
    int e = info.x, deg = info.y, end = info.x + deg;
    const u16x8* f8 = (const u16x8*)g2b;
    float acc[8];
    #pragma unroll
    for (int j = 0; j < 8; j++) acc[j] = 0.0f;
    for (; e + 4 <= end; e += 4) {
        int s0 = edge_src[e + 0];
        int s1 = edge_src[e + 1];
        int s2 = edge_src[e + 2];
        int s3 = edge_src[e + 3];
        u16x8 v0 = f8[(size_t)s0 * 8 + q];
        u16x8 v1 = f8[(size_t)s1 * 8 + q];
        u16x8 v2 = f8[(size_t)s2 * 8 + q];
        u16x8 v3 = f8[(size_t)s3 * 8 + q];
        #pragma unroll
        for (int j = 0; j < 8; j++)
            acc[j] += (b2f(v0[j]) + b2f(v1[j])) + (b2f(v2[j]) + b2f(v3[j]));
    }
    for (; e < end; e++) {
        u16x8 v0 = f8[(size_t)edge_src[e] * 8 + q];
        #pragma unroll
        for (int j = 0; j < 8; j++) acc[j] += b2f(v0[j]);
    }
    float inv = (deg > 0) ? 1.0f / (float)deg : 0.0f;

    u16x8 rv = ((const u16x8*)r2b)[tid];            // node*8 + q
    float4 blo = ((const float4*)b2)[q * 2];
    float4 bhi = ((const float4*)b2)[q * 2 + 1];
    float v[8];
    v[0] = acc[0] * inv + blo.x + b2f(rv[0]);
    v[1] = acc[1] * inv + blo.y + b2f(rv[1]);
    v[2] = acc[2] * inv + blo.z + b2f(rv[2]);
    v[3] = acc[3] * inv + blo.w + b2f(rv[3]);
    v[4] = acc[4] * inv + bhi.x + b2f(rv[4]);
    v[5] = acc[5] * inv + bhi.y + b2f(rv[5]);
    v[6] = acc[6] * inv + bhi.z + b2f(rv[6]);
    v[7] = acc[7] * inv + bhi.w + b2f(rv[7]);

    float mx = v[0];
    #pragma unroll
    for (int j = 1; j < 8; j++) mx = fmaxf(mx, v[j]);
    mx = fmaxf(mx, __shfl_xor(mx, 1, 64));
    mx = fmaxf(mx, __shfl_xor(mx, 2, 64));
    mx = fmaxf(mx, __shfl_xor(mx, 4, 64));
    float s = 0.0f;
    #pragma unroll
    for (int j = 0; j < 8; j++) s += expf(v[j] - mx);
    s += __shfl_xor(s, 1, 64);
    s += __shfl_xor(s, 2, 64);
    s += __shfl_xor(s, 4, 64);
    float lg = mx + logf(s);

    float4 o0 = make_float4(v[0] - lg, v[1] - lg, v[2] - lg, v[3] - lg);
    float4 o1 = make_float4(v[4] - lg, v[5] - lg, v[6] - lg, v[7] - lg);
    float4* op = (float4*)(out + (size_t)node * 64 + q * 8);
    op[0] = o0;
    op[1] = o1;
}

// ===========================================================================
extern "C" void kernel_launch(void* const* d_in, const int* in_sizes, int n_in,
                              void* d_out, int out_size, void* d_ws, size_t ws_size,
                              hipStream_t stream)
{
    const float* x   = (const float*)d_in[0];
    const int*   ei  = (const int*)d_in[1];
    const float* W1l = (const float*)d_in[2];
    const float* b1  = (const float*)d_in[3];
    const float* W1r = (const float*)d_in[4];
    const float* W2l = (const float*)d_in[5];
    const float* b2  = (const float*)d_in[6];
    const float* W2r = (const float*)d_in[7];
    float* out = (float*)d_out;

    int E = in_sizes[1] / 2;
    const int* src = ei;
    const int* dst = ei + E;

    // Per-bucket pair capacity: 1.5x mean (mean 6400, sigma 80 -> +40 sigma).
    int pairCap = ((E / NBUCKET) * 3 / 2 + 255) / 256 * 256;   // 9600 for E=1.6M

    // Workspace layout (16B-aligned sections)
    char* ws = (char*)d_ws;
    int*  bucketCursor = (int*)ws;   ws += ((size_t)NBUCKET * 4 + 15) / 16 * 16;
    int2* pairs        = (int2*)ws;  ws += (size_t)NBUCKET * pairCap * 8;
    int*  edge_src     = (int*)ws;   ws += (size_t)NBUCKET * pairCap * 4;
    int2* nodeInfo     = (int2*)ws;  ws += (size_t)N_NODES * 8;
    unsigned short* xb   = (unsigned short*)ws;  ws += (size_t)N_NODES * 128 * 2;
    unsigned char*  xq   = (unsigned char*)ws;   ws += (size_t)N_NODES * 128;
    unsigned short* a1b  = (unsigned short*)ws;  ws += (size_t)N_NODES * 128 * 2;
    unsigned short* g2b  = (unsigned short*)ws;  ws += (size_t)N_NODES * 64 * 2;
    unsigned short* r2b  = (unsigned short*)ws;  ws += (size_t)N_NODES * 64 * 2;
    unsigned short* Wc1f = (unsigned short*)ws;  ws += 128 * 256 * 2;
    unsigned short* W2lf = (unsigned short*)ws;  ws += 64 * 128 * 2;
    unsigned short* W2rf = (unsigned short*)ws;  ws += 64 * 128 * 2;

    // 1. prep: bf16+fp8 casts + weight swizzle + bucket cursor init
    prep_kernel<<<12693, 256, 0, stream>>>(
        x, W1l, W1r, W2l, W2r, xb, xq, Wc1f, W2lf, W2rf, bucketCursor, pairCap);

    // 2. bucket edges by dst range (block-exclusive chunk writes)
    {
        const int EPB = 1024 * BK_EPT;
        bucket_kernel<<<(E + EPB - 1) / EPB, 1024, 0, stream>>>(
            src, dst, bucketCursor, pairs, E);
    }

    // 3. per-bucket LDS hist/scan/place -> edge_src + nodeInfo (beg,deg)
    fill_kernel<<<NBUCKET, 1024, 0, stream>>>(
        pairs, bucketCursor, edge_src, nodeInfo, pairCap);

    // 4. layer-1 aggregation from fp8 table (D=128, 8 lanes/node)
    gather_fp8_kernel<<<(N_NODES * 8) / 256, 256, 0, stream>>>(
        xq, edge_src, nodeInfo, a1b);

    // 5. fused dense block: layer1 GEMM + relu + both layer2 matmuls
    fused_l1_kernel<<<(N_NODES + 127) / 128, 256, 0, stream>>>(
        a1b, xb, Wc1f, b1, W2lf, W2rf, g2b, r2b);

    // 6. layer-2 aggregation fused with bias + residual + log_softmax
    gather_final_kernel<<<(N_NODES * 8) / 256, 256, 0, stream>>>(
        g2b, edge_src, nodeInfo, r2b, b2, out);
}